// Round 1
// baseline (26001.541 us; speedup 1.0000x reference)
//
#include <hip/hip_runtime.h>
#include <hip/hip_bf16.h>

// GRU, T=2048, B=64, D=H=512, fp32.
// Strategy:
//   1) prep_weights: split fp32 W[512,1024] into x-part / h-part, cast bf16.
//   2) xpre_gemm:    bf16 MFMA GEMM precomputing all x-side gate pre-acts
//                    (+bias) into fp32 Xbuf (runtime-chunked to fit ws).
//   3) gru_rec:      128 blocks x 128 threads; 4 row-clusters x 32 column
//                    slices; weight slices LDS-resident. Cross-block exchange
//                    of h and r*h via TAGGED DWORDS: (bf16<<16)|step_tag,
//                    sc0+sc1 fire-and-forget stores, consumers poll-load their
//                    own MFMA fragments and MFMA each fragment the moment the
//                    whole wave sees its tags fresh. No counters, no fences,
//                    no __syncthreads in the recurrence loop; waves decoupled.

#define T_STEPS 2048
#define BATCH   64
#define HID     512

typedef __attribute__((ext_vector_type(8))) short short8;
typedef __attribute__((ext_vector_type(8))) unsigned short ushort8;
typedef __attribute__((ext_vector_type(4))) float f32x4;
typedef __attribute__((ext_vector_type(4))) unsigned int u32x4;

__device__ __forceinline__ unsigned short f2bf(float f) {
  __hip_bfloat16 h = __float2bfloat16(f);
  return *reinterpret_cast<unsigned short*>(&h);
}
__device__ __forceinline__ float bf2f(unsigned short u) {
  __hip_bfloat16 h = *reinterpret_cast<__hip_bfloat16*>(&u);
  return __bfloat162float(h);
}

// Coherent (bypass L1+L2, served at the device coherence point) loads.
__device__ __forceinline__ u32x4 ld_cohx4(const unsigned int* p) {
  u32x4 r;
  asm volatile("global_load_dwordx4 %0, %1, off sc0 sc1"
               : "=v"(r) : "v"(p) : "memory");
  return r;
}
__device__ __forceinline__ unsigned int ld_coh(const unsigned int* p) {
  unsigned int r;
  asm volatile("global_load_dword %0, %1, off sc0 sc1"
               : "=v"(r) : "v"(p) : "memory");
  return r;
}

// ---------------------------------------------------------------- prep
__global__ __launch_bounds__(256) void prep_weights(
    const float* __restrict__ Wr, const float* __restrict__ br,
    const float* __restrict__ Wz, const float* __restrict__ bz,
    const float* __restrict__ Wg, const float* __restrict__ bg,
    unsigned short* __restrict__ whb,   // [3][512][512] bf16 (h-part)
    unsigned short* __restrict__ wxb,   // [1536][512]   bf16 (x-part)
    float* __restrict__ bias)           // [1536]
{
  int g = blockIdx.x >> 9;        // 0..2
  int n = blockIdx.x & 511;       // output row
  const float* W  = (g == 0) ? Wr : (g == 1) ? Wz : Wg;
  const float* bs = (g == 0) ? br : (g == 1) ? bz : bg;
  const float* row = W + (size_t)n * 1024;
  size_t obase = ((size_t)g * 512 + n) * 512;
  for (int k = threadIdx.x; k < 512; k += 256) {
    wxb[obase + k] = f2bf(row[k]);         // x-part: cols [0,512)
    whb[obase + k] = f2bf(row[512 + k]);   // h-part: cols [512,1024)
  }
  if (threadIdx.x == 0) bias[g * 512 + n] = bs[n];
}

// ---------------------------------------------------------------- x GEMM
__global__ __launch_bounds__(256) void xpre_gemm(
    const float* __restrict__ x,              // [rows][512]
    const unsigned short* __restrict__ wxb,   // [1536][512]
    const float* __restrict__ bias,           // [1536]
    float* __restrict__ xbuf)                 // [rows][1536]
{
  __shared__ __align__(16) unsigned short aT[128][40];  // +8 pad: 2-way banks
  __shared__ __align__(16) unsigned short bT[128][40];
  const int tid = threadIdx.x;
  const int bm = blockIdx.x, bn = blockIdx.y;
  const int wv = tid >> 6, lane = tid & 63, l15 = lane & 15, quad = lane >> 4;
  const int m_off = (wv & 1) * 64, n_off = (wv >> 1) * 64;
  f32x4 acc[4][4] = {};
  const int r = tid >> 1, ks = (tid & 1) * 16;
  const float* ag = x + (size_t)(bm * 128 + r) * 512 + ks;
  const unsigned short* bgp = wxb + (size_t)(bn * 128 + r) * 512 + ks;
  for (int kb = 0; kb < 16; ++kb) {
    const f32x4* af4 = (const f32x4*)(ag + kb * 32);
    f32x4 v0 = af4[0], v1 = af4[1], v2 = af4[2], v3 = af4[3];
    ushort8 u0 = { f2bf(v0[0]), f2bf(v0[1]), f2bf(v0[2]), f2bf(v0[3]),
                   f2bf(v1[0]), f2bf(v1[1]), f2bf(v1[2]), f2bf(v1[3]) };
    ushort8 u1 = { f2bf(v2[0]), f2bf(v2[1]), f2bf(v2[2]), f2bf(v2[3]),
                   f2bf(v3[0]), f2bf(v3[1]), f2bf(v3[2]), f2bf(v3[3]) };
    *(ushort8*)&aT[r][ks]     = u0;
    *(ushort8*)&aT[r][ks + 8] = u1;
    const ushort8* bv = (const ushort8*)(bgp + kb * 32);
    *(ushort8*)&bT[r][ks]     = bv[0];
    *(ushort8*)&bT[r][ks + 8] = bv[1];
    __syncthreads();
    short8 afr[4], bfr[4];
    #pragma unroll
    for (int mt = 0; mt < 4; ++mt)
      afr[mt] = *(const short8*)&aT[m_off + mt * 16 + l15][quad * 8];
    #pragma unroll
    for (int nt = 0; nt < 4; ++nt)
      bfr[nt] = *(const short8*)&bT[n_off + nt * 16 + l15][quad * 8];
    #pragma unroll
    for (int mt = 0; mt < 4; ++mt)
      #pragma unroll
      for (int nt = 0; nt < 4; ++nt)
        acc[mt][nt] = __builtin_amdgcn_mfma_f32_16x16x32_bf16(
            afr[mt], bfr[nt], acc[mt][nt], 0, 0, 0);
    __syncthreads();
  }
  #pragma unroll
  for (int nt = 0; nt < 4; ++nt) {
    int n_g = bn * 128 + n_off + nt * 16 + l15;
    float bv = bias[n_g];
    #pragma unroll
    for (int mt = 0; mt < 4; ++mt) {
      int m_g = bm * 128 + m_off + mt * 16 + quad * 4;
      #pragma unroll
      for (int i = 0; i < 4; ++i)
        xbuf[(size_t)(m_g + i) * 1536 + n_g] = acc[mt][nt][i] + bv;
    }
  }
}

// ---------------------------------------------------------------- recurrence
// Poll 16 tagged-dword fragments (8 dwords each, layout = MFMA A-frag of one
// 16x512 tile row-block) and MFMA each against its LDS weight B-frag as soon
// as the whole wave has it fresh. Optionally (EX) also poll 4 extra scalar
// dwords (the lane's own h values for the r*h product).
template<bool EX>
__device__ __forceinline__ void poll_gemm(
    const unsigned int* __restrict__ prow,   // buf + (row0+l15)*512 + quad*8
    const unsigned short* wbase,             // &wlds[g][l15][quad*8]
    const unsigned int* __restrict__ pex,    // lane extra base (stride 512)
    unsigned int tag, f32x4& accA, f32x4& accB, unsigned int* exv)
{
  u32x4 d0[16], d1[16];
  unsigned int pend  = EX ? 0x1ffffu : 0xffffu;   // wave-uniform
  unsigned int fresh = 0u;                        // per-lane
  while (pend) {
    #pragma unroll
    for (int kb = 0; kb < 16; ++kb)
      if (((pend >> kb) & 1u) && !((fresh >> kb) & 1u)) {
        d0[kb] = ld_cohx4(prow + kb * 32);
        d1[kb] = ld_cohx4(prow + kb * 32 + 4);
      }
    if (EX) {
      if (((pend >> 16) & 1u) && !((fresh >> 16) & 1u)) {
        #pragma unroll
        for (int i = 0; i < 4; ++i) exv[i] = ld_coh(pex + (size_t)i * 512);
      }
    }
    asm volatile("s_waitcnt vmcnt(0)" ::: "memory");
    __builtin_amdgcn_sched_barrier(0);
    #pragma unroll
    for (int kb = 0; kb < 16; ++kb)
      if (((pend >> kb) & 1u) && !((fresh >> kb) & 1u)) {
        unsigned int bad = 0u;
        #pragma unroll
        for (int j = 0; j < 4; ++j) {
          bad |= (d0[kb][j] ^ tag) << 16;   // low16 must equal tag
          bad |= (d1[kb][j] ^ tag) << 16;
        }
        if (bad == 0u) fresh |= 1u << kb;
      }
    if (EX) {
      if (((pend >> 16) & 1u) && !((fresh >> 16) & 1u)) {
        unsigned int bad = 0u;
        #pragma unroll
        for (int i = 0; i < 4; ++i) bad |= (exv[i] ^ tag) << 16;
        if (bad == 0u) fresh |= 1u << 16;
      }
    }
    unsigned int ready = 0u;
    #pragma unroll
    for (int kb = 0; kb < (EX ? 17 : 16); ++kb)
      if ((pend >> kb) & 1u)
        if (__all((int)((fresh >> kb) & 1u))) ready |= 1u << kb;
    #pragma unroll
    for (int kb = 0; kb < 16; ++kb)
      if ((ready >> kb) & 1u) {
        u32x4 w;
        w[0] = (d0[kb][0] >> 16) | (d0[kb][1] & 0xffff0000u);
        w[1] = (d0[kb][2] >> 16) | (d0[kb][3] & 0xffff0000u);
        w[2] = (d1[kb][0] >> 16) | (d1[kb][1] & 0xffff0000u);
        w[3] = (d1[kb][2] >> 16) | (d1[kb][3] & 0xffff0000u);
        short8 av = __builtin_bit_cast(short8, w);
        short8 bv = *(const short8*)(wbase + kb * 32);
        if (kb & 1)
          accB = __builtin_amdgcn_mfma_f32_16x16x32_bf16(av, bv, accB, 0, 0, 0);
        else
          accA = __builtin_amdgcn_mfma_f32_16x16x32_bf16(av, bv, accA, 0, 0, 0);
      }
    pend &= ~ready;
  }
}

__global__ __launch_bounds__(128, 1) void gru_rec(
    const float* __restrict__ xbuf,           // [cs*64][1536] fp32
    const unsigned short* __restrict__ whb,   // [3][512][512] bf16
    float* __restrict__ dout,
    float* __restrict__ hstateF,              // [64][512] fp32 chunk carry
    unsigned int* __restrict__ hbufT,         // [2][64][512] tagged dwords
    unsigned int* __restrict__ rhbufT,        // [64][512]    tagged dwords
    int t0, int cs)
{
  const int tid = threadIdx.x;
  const int bid = blockIdx.x;
  const int c = bid & 3;
  const int s = bid >> 2;
  const int wv = tid >> 6, lane = tid & 63, l15 = lane & 15, quad = lane >> 4;
  const int n_glob = s * 16 + l15;
  const int m_base = quad * 4;
  const int row0 = c * 16;
  __shared__ __align__(16) unsigned short wlds[3][16][520];  // 48.8 KB

  for (int v = tid; v < 3 * 16 * 64; v += 128) {   // ushort8 granules
    int g  = v >> 10;
    int rr = (v >> 6) & 15;
    int kv = (v & 63) * 8;
    *(ushort8*)&wlds[g][rr][kv] =
        *(const ushort8*)&whb[((size_t)g * 512 + s * 16 + rr) * 512 + kv];
  }

  float hz[4] = {0.f, 0.f, 0.f, 0.f};   // fp32 own-tile state (wave0)
  if (t0 > 0 && wv == 0) {
    #pragma unroll
    for (int i = 0; i < 4; ++i)
      hz[i] = hstateF[(size_t)(row0 + m_base + i) * 512 + n_glob];
  }
  __syncthreads();   // weights resident; from here waves are fully decoupled

  if (wv == 0) {
    // ---- wave0: z (gate 1), then g (gate 2) + h update ----
    const unsigned short* wzb = &wlds[1][l15][quad * 8];
    const unsigned short* wgb = &wlds[2][l15][quad * 8];
    for (int t = t0; t < t0 + cs; ++t) {
      const int tl = t - t0;
      const unsigned int tag = (unsigned int)t & 0xffffu;
      const float* xrow =
          xbuf + (size_t)(tl * 64 + row0 + m_base) * 1536 + n_glob;
      float xa[4], xg[4];
      #pragma unroll
      for (int i = 0; i < 4; ++i) {
        xa[i] = xrow[(size_t)i * 1536 + 512];    // Xz
        xg[i] = xrow[(size_t)i * 1536 + 1024];   // Xg
      }
      f32x4 acc = {0.f, 0.f, 0.f, 0.f}, acc2 = {0.f, 0.f, 0.f, 0.f};
      if (t > 0) {
        const unsigned int* prow = hbufT + (size_t)(t & 1) * (BATCH * 512)
                                 + (size_t)(row0 + l15) * 512 + quad * 8;
        poll_gemm<false>(prow, wzb, nullptr, tag, acc, acc2, nullptr);
      }
      float zv[4];
      #pragma unroll
      for (int i = 0; i < 4; ++i)
        zv[i] = 1.f / (1.f + __expf(-(acc[i] + acc2[i] + xa[i])));
      f32x4 ag = {0.f, 0.f, 0.f, 0.f}, ag2 = {0.f, 0.f, 0.f, 0.f};
      if (t > 0) {
        const unsigned int* prow =
            rhbufT + (size_t)(row0 + l15) * 512 + quad * 8;
        poll_gemm<false>(prow, wgb, nullptr, tag, ag, ag2, nullptr);
      }
      unsigned int* hTn = hbufT + (size_t)((t + 1) & 1) * (BATCH * 512);
      const unsigned int ntag = (unsigned int)(t + 1) & 0xffffu;
      #pragma unroll
      for (int i = 0; i < 4; ++i) {
        float pre = ag[i] + ag2[i] + xg[i];
        float e  = __expf(-2.f * fabsf(pre));   // overflow-safe tanh
        float th = (1.f - e) / (1.f + e);
        th = (pre < 0.f) ? -th : th;
        float hn = zv[i] * hz[i] + (1.f - zv[i]) * th;
        hz[i] = hn;
        size_t ridx = (size_t)(row0 + m_base + i) * 512 + n_glob;
        dout[(size_t)t * BATCH * 512 + ridx] = hn;
        __hip_atomic_store(&hTn[ridx],
            ((unsigned int)f2bf(hn) << 16) | ntag,
            __ATOMIC_RELAXED, __HIP_MEMORY_SCOPE_AGENT);
        if (t == T_STEPS - 1)
          dout[(size_t)T_STEPS * BATCH * 512 + ridx] = hn;   // h_final
        if (t == t0 + cs - 1)
          hstateF[ridx] = hn;                                 // chunk carry
      }
    }
  } else {
    // ---- wave1: r (gate 0), r*h broadcast ----
    const unsigned short* wrb = &wlds[0][l15][quad * 8];
    for (int t = (t0 == 0 ? 1 : t0); t < t0 + cs; ++t) {
      const int tl = t - t0;
      const unsigned int tag = (unsigned int)t & 0xffffu;
      const float* xrow =
          xbuf + (size_t)(tl * 64 + row0 + m_base) * 1536 + n_glob;
      float xa[4];
      #pragma unroll
      for (int i = 0; i < 4; ++i) xa[i] = xrow[(size_t)i * 1536];  // Xr
      const unsigned int* hT = hbufT + (size_t)(t & 1) * (BATCH * 512);
      const unsigned int* prow = hT + (size_t)(row0 + l15) * 512 + quad * 8;
      const unsigned int* pex  = hT + (size_t)(row0 + m_base) * 512 + n_glob;
      f32x4 acc = {0.f, 0.f, 0.f, 0.f}, acc2 = {0.f, 0.f, 0.f, 0.f};
      unsigned int exv[4];
      poll_gemm<true>(prow, wrb, pex, tag, acc, acc2, exv);
      #pragma unroll
      for (int i = 0; i < 4; ++i) {
        float rv  = 1.f / (1.f + __expf(-(acc[i] + acc2[i] + xa[i])));
        float hvf = bf2f((unsigned short)(exv[i] >> 16));
        size_t ridx = (size_t)(row0 + m_base + i) * 512 + n_glob;
        __hip_atomic_store(&rhbufT[ridx],
            ((unsigned int)f2bf(rv * hvf) << 16) | tag,
            __ATOMIC_RELAXED, __HIP_MEMORY_SCOPE_AGENT);
      }
    }
  }
}

// ---------------------------------------------------------------- launch
extern "C" void kernel_launch(void* const* d_in, const int* in_sizes, int n_in,
                              void* d_out, int out_size, void* d_ws, size_t ws_size,
                              hipStream_t stream) {
  const float* x  = (const float*)d_in[0];
  const float* Wr = (const float*)d_in[1];
  const float* br = (const float*)d_in[2];
  const float* Wz = (const float*)d_in[3];
  const float* bz = (const float*)d_in[4];
  const float* Wg = (const float*)d_in[5];
  const float* bg = (const float*)d_in[6];
  float* out = (float*)d_out;
  char* ws = (char*)d_ws;

  // ws layout (256B-aligned offsets)
  float* bias            = (float*)(ws + 0);                // 6 KB
  float* hstateF         = (float*)(ws + 8192);             // 128 KB
  unsigned int* hbufT    = (unsigned int*)(ws + 139264);    // 256 KB tagged h
  unsigned int* rhbufT   = (unsigned int*)(ws + 401408);    // 128 KB tagged rh
  unsigned short* whb    = (unsigned short*)(ws + 532480);  // 1.5 MB
  unsigned short* wxb    = (unsigned short*)(ws + 2105344); // 1.5 MB
  float* xbuf            = (float*)(ws + 3678208);          // cs*64*1536*4

  int cs = T_STEPS;   // largest chunk of timesteps whose Xbuf fits in ws
  while (cs > 8 &&
         3678208ull + (unsigned long long)cs * 64 * 1536 * 4 >
             (unsigned long long)ws_size)
    cs >>= 1;

  // tag-clean the exchange buffers (tag 0 never matches any expected t>=1)
  hipMemsetAsync((void*)(ws + 139264), 0, 393216, stream);
  prep_weights<<<1536, 256, 0, stream>>>(Wr, br, Wz, bz, Wg, bg, whb, wxb, bias);
  for (int t0 = 0; t0 < T_STEPS; t0 += cs) {
    xpre_gemm<<<dim3((cs * 64) / 128, 12), 256, 0, stream>>>(
        x + (size_t)t0 * 64 * 512, wxb, bias, xbuf);
    gru_rec<<<128, 128, 0, stream>>>(xbuf, whb, out, hstateF, hbufT, rhbufT,
                                     t0, cs);
  }
}

// Round 3
// 13223.233 us; speedup vs baseline: 1.9664x; 1.9664x over previous
//
#include <hip/hip_runtime.h>
#include <hip/hip_bf16.h>

// GRU, T=2048, B=64, D=H=512, fp32.
// Strategy:
//   1) prep_weights: split fp32 W[512,1024] into x-part / h-part, cast bf16.
//   2) xpre_gemm:    bf16 MFMA GEMM precomputing all x-side gate pre-acts
//                    (+bias) into fp32 Xbuf (runtime-chunked to fit ws).
//   3) gru_rec:      64 blocks x 256 threads; 4 row-clusters x 16 col-slices
//                    (32 cols each, weights LDS-resident, 96KB). Cross-block
//                    exchange of h and r*h as per-cluster CONTIGUOUS tagged
//                    dword arrays [16][512]: (bf16<<16)|t. Producers do
//                    fire-and-forget sc0+sc1 dword stores; each block
//                    poll-loads the 32KB cluster image COALESCED (32
//                    consecutive dwords per thread), strips tags into LDS,
//                    and all GEMM fragments read from LDS. No counters, no
//                    fences, no L2 invalidates.

#define T_STEPS 2048
#define BATCH   64
#define HID     512

typedef __attribute__((ext_vector_type(8))) short short8;
typedef __attribute__((ext_vector_type(8))) unsigned short ushort8;
typedef __attribute__((ext_vector_type(4))) unsigned short us4;
typedef __attribute__((ext_vector_type(4))) float f32x4;
typedef __attribute__((ext_vector_type(4))) unsigned int u32x4;

__device__ __forceinline__ unsigned short f2bf(float f) {
  __hip_bfloat16 h = __float2bfloat16(f);
  return *reinterpret_cast<unsigned short*>(&h);
}
__device__ __forceinline__ float bf2f(unsigned short u) {
  __hip_bfloat16 h = *reinterpret_cast<__hip_bfloat16*>(&u);
  return __bfloat162float(h);
}

// Coherent (bypass L1+L2, served at the device coherence point) load.
__device__ __forceinline__ u32x4 ld_cohx4(const unsigned int* p) {
  u32x4 r;
  asm volatile("global_load_dwordx4 %0, %1, off sc0 sc1"
               : "=v"(r) : "v"(p) : "memory");
  return r;
}

// ---------------------------------------------------------------- prep
__global__ __launch_bounds__(256) void prep_weights(
    const float* __restrict__ Wr, const float* __restrict__ br,
    const float* __restrict__ Wz, const float* __restrict__ bz,
    const float* __restrict__ Wg, const float* __restrict__ bg,
    unsigned short* __restrict__ whb,   // [3][512][512] bf16 (h-part)
    unsigned short* __restrict__ wxb,   // [1536][512]   bf16 (x-part)
    float* __restrict__ bias)           // [1536]
{
  int g = blockIdx.x >> 9;        // 0..2
  int n = blockIdx.x & 511;       // output row
  const float* W  = (g == 0) ? Wr : (g == 1) ? Wz : Wg;
  const float* bs = (g == 0) ? br : (g == 1) ? bz : bg;
  const float* row = W + (size_t)n * 1024;
  size_t obase = ((size_t)g * 512 + n) * 512;
  for (int k = threadIdx.x; k < 512; k += 256) {
    wxb[obase + k] = f2bf(row[k]);         // x-part: cols [0,512)
    whb[obase + k] = f2bf(row[512 + k]);   // h-part: cols [512,1024)
  }
  if (threadIdx.x == 0) bias[g * 512 + n] = bs[n];
}

// ---------------------------------------------------------------- x GEMM
__global__ __launch_bounds__(256) void xpre_gemm(
    const float* __restrict__ x,              // [rows][512]
    const unsigned short* __restrict__ wxb,   // [1536][512]
    const float* __restrict__ bias,           // [1536]
    float* __restrict__ xbuf)                 // [rows][1536]
{
  __shared__ __align__(16) unsigned short aT[128][40];  // +8 pad: 2-way banks
  __shared__ __align__(16) unsigned short bT[128][40];
  const int tid = threadIdx.x;
  const int bm = blockIdx.x, bn = blockIdx.y;
  const int wv = tid >> 6, lane = tid & 63, l15 = lane & 15, quad = lane >> 4;
  const int m_off = (wv & 1) * 64, n_off = (wv >> 1) * 64;
  f32x4 acc[4][4] = {};
  const int r = tid >> 1, ks = (tid & 1) * 16;
  const float* ag = x + (size_t)(bm * 128 + r) * 512 + ks;
  const unsigned short* bgp = wxb + (size_t)(bn * 128 + r) * 512 + ks;
  for (int kb = 0; kb < 16; ++kb) {
    const f32x4* af4 = (const f32x4*)(ag + kb * 32);
    f32x4 v0 = af4[0], v1 = af4[1], v2 = af4[2], v3 = af4[3];
    ushort8 u0 = { f2bf(v0[0]), f2bf(v0[1]), f2bf(v0[2]), f2bf(v0[3]),
                   f2bf(v1[0]), f2bf(v1[1]), f2bf(v1[2]), f2bf(v1[3]) };
    ushort8 u1 = { f2bf(v2[0]), f2bf(v2[1]), f2bf(v2[2]), f2bf(v2[3]),
                   f2bf(v3[0]), f2bf(v3[1]), f2bf(v3[2]), f2bf(v3[3]) };
    *(ushort8*)&aT[r][ks]     = u0;
    *(ushort8*)&aT[r][ks + 8] = u1;
    const ushort8* bv = (const ushort8*)(bgp + kb * 32);
    *(ushort8*)&bT[r][ks]     = bv[0];
    *(ushort8*)&bT[r][ks + 8] = bv[1];
    __syncthreads();
    short8 afr[4], bfr[4];
    #pragma unroll
    for (int mt = 0; mt < 4; ++mt)
      afr[mt] = *(const short8*)&aT[m_off + mt * 16 + l15][quad * 8];
    #pragma unroll
    for (int nt = 0; nt < 4; ++nt)
      bfr[nt] = *(const short8*)&bT[n_off + nt * 16 + l15][quad * 8];
    #pragma unroll
    for (int mt = 0; mt < 4; ++mt)
      #pragma unroll
      for (int nt = 0; nt < 4; ++nt)
        acc[mt][nt] = __builtin_amdgcn_mfma_f32_16x16x32_bf16(
            afr[mt], bfr[nt], acc[mt][nt], 0, 0, 0);
    __syncthreads();
  }
  #pragma unroll
  for (int nt = 0; nt < 4; ++nt) {
    int n_g = bn * 128 + n_off + nt * 16 + l15;
    float bv = bias[n_g];
    #pragma unroll
    for (int mt = 0; mt < 4; ++mt) {
      int m_g = bm * 128 + m_off + mt * 16 + quad * 4;
      #pragma unroll
      for (int i = 0; i < 4; ++i)
        xbuf[(size_t)(m_g + i) * 1536 + n_g] = acc[mt][nt][i] + bv;
    }
  }
}

// ---------------------------------------------------------------- recurrence
// Poll a 32KB contiguous tagged cluster image ([16 rows][512 cols] dwords,
// (bf16<<16)|tag) with coalesced loads; when this thread's 32 dwords are all
// fresh, strip tags into LDS [16][520] bf16. Block-level completion via the
// caller's __syncthreads.
__device__ __forceinline__ void poll_stage(
    const unsigned int* __restrict__ base, unsigned int tag,
    unsigned short (*__restrict__ st)[520], int tid)
{
  u32x4 d[8];
  unsigned int stale = 0xffu;
  while (stale) {
    #pragma unroll
    for (int j = 0; j < 8; ++j)
      if ((stale >> j) & 1u)
        d[j] = ld_cohx4(base + ((j * 256 + tid) << 2));
    asm volatile("s_waitcnt vmcnt(0)" ::: "memory");
    __builtin_amdgcn_sched_barrier(0);
    unsigned int prev = stale;
    #pragma unroll
    for (int j = 0; j < 8; ++j)
      if ((stale >> j) & 1u) {
        unsigned int bad = 0u;
        #pragma unroll
        for (int k = 0; k < 4; ++k) bad |= (d[j][k] ^ tag) << 16;
        if (bad == 0u) stale &= ~(1u << j);
      }
    if (stale && stale == prev) __builtin_amdgcn_s_sleep(1);
  }
  #pragma unroll
  for (int j = 0; j < 8; ++j) {
    int dw = (j * 256 + tid) << 2;
    int row = dw >> 9, col = dw & 511;
    us4 u = { (unsigned short)(d[j][0] >> 16), (unsigned short)(d[j][1] >> 16),
              (unsigned short)(d[j][2] >> 16), (unsigned short)(d[j][3] >> 16) };
    *(us4*)&st[row][col] = u;
  }
}

__global__ __launch_bounds__(256, 1) void gru_rec(
    const float* __restrict__ xbuf,           // [cs*64][1536] fp32
    const unsigned short* __restrict__ whb,   // [3][512][512] bf16
    float* __restrict__ dout,
    float* __restrict__ hstateF,              // [64][512] fp32 chunk carry
    unsigned int* __restrict__ PhT,           // [2][4][16][512] tagged dwords
    unsigned int* __restrict__ PrhT,          // [4][16][512]    tagged dwords
    int t0, int cs)
{
  const int tid = threadIdx.x;
  const int bid = blockIdx.x;              // 64 blocks
  const int c = bid & 3, s = bid >> 2;     // cluster (16 rows), 32-col slice
  const int wv = tid >> 6, lane = tid & 63, l15 = lane & 15, quad = lane >> 4;
  const int row0 = c * 16, m_base = quad * 4;
  const bool zgw = (wv < 2);               // waves 0,1: z+g+update; 2,3: r
  const int ct = zgw ? wv : (wv - 2);      // 16-col tile within the slice
  const int colg = s * 32 + ct * 16 + l15; // global hidden col of C/D frag
  __shared__ __align__(16) unsigned short wlds[3][32][520];  // 97.5 KB
  __shared__ __align__(16) unsigned short hst[16][520];      // 16.25 KB
  __shared__ __align__(16) unsigned short rst[16][520];      // 16.25 KB

  for (int v = tid; v < 3 * 32 * 64; v += 256) {   // ushort8 granules
    int g  = v >> 11;
    int rr = (v >> 6) & 31;
    int kv = (v & 63) * 8;
    *(ushort8*)&wlds[g][rr][kv] =
        *(const ushort8*)&whb[((size_t)g * 512 + s * 32 + rr) * 512 + kv];
  }

  float hz[4] = {0.f, 0.f, 0.f, 0.f};   // fp32 own-tile state (zg-waves)
  if (t0 > 0 && zgw) {
    #pragma unroll
    for (int i = 0; i < 4; ++i)
      hz[i] = hstateF[(size_t)(row0 + m_base + i) * 512 + colg];
  }
  __syncthreads();

  const unsigned int* Prhc = PrhT + c * 8192;

  for (int t = t0; t < t0 + cs; ++t) {
    const int tl = t - t0;
    const unsigned int tag = (unsigned int)t;
    // prefetch x-side pre-activations (overlaps the h wait)
    const float* xrow = xbuf + (size_t)(tl * 64 + row0 + m_base) * 1536 + colg;
    float xa[4], xg[4];
    if (zgw) {
      #pragma unroll
      for (int i = 0; i < 4; ++i) {
        xa[i] = xrow[(size_t)i * 1536 + 512];    // Xz
        xg[i] = xrow[(size_t)i * 1536 + 1024];   // Xg
      }
    } else {
      #pragma unroll
      for (int i = 0; i < 4; ++i) xa[i] = xrow[(size_t)i * 1536];  // Xr
    }

    if (t > 0)
      poll_stage(PhT + (size_t)(t & 1) * 32768 + c * 8192, tag, hst, tid);
    __syncthreads();   // hst = h_t (bf16) for the whole cluster

    // phase B: zg-waves -> z; r-waves -> r + r*h broadcast
    f32x4 a0 = {0.f, 0.f, 0.f, 0.f}, a1 = {0.f, 0.f, 0.f, 0.f};
    if (t > 0) {
      const int gate = zgw ? 1 : 0;
      const unsigned short* wb = &wlds[gate][ct * 16 + l15][quad * 8];
      #pragma unroll
      for (int kb = 0; kb < 16; kb += 2) {   // 2 chains for MFMA ILP
        a0 = __builtin_amdgcn_mfma_f32_16x16x32_bf16(
            *(const short8*)&hst[l15][kb * 32 + quad * 8],
            *(const short8*)(wb + kb * 32), a0, 0, 0, 0);
        a1 = __builtin_amdgcn_mfma_f32_16x16x32_bf16(
            *(const short8*)&hst[l15][(kb + 1) * 32 + quad * 8],
            *(const short8*)(wb + (kb + 1) * 32), a1, 0, 0, 0);
      }
    }
    float zv[4];
    if (zgw) {
      #pragma unroll
      for (int i = 0; i < 4; ++i)
        zv[i] = 1.f / (1.f + __expf(-(a0[i] + a1[i] + xa[i])));
    } else if (t > 0) {
      unsigned int* rb = PrhT + c * 8192;
      #pragma unroll
      for (int i = 0; i < 4; ++i) {
        float rv  = 1.f / (1.f + __expf(-(a0[i] + a1[i] + xa[i])));
        float hvf = bf2f(hst[m_base + i][colg]);
        __hip_atomic_store(&rb[(m_base + i) * 512 + colg],
            ((unsigned int)f2bf(rv * hvf) << 16) | tag,
            __ATOMIC_RELAXED, __HIP_MEMORY_SCOPE_AGENT);
      }
    }

    if (t > 0)
      poll_stage(Prhc, tag, rst, tid);
    __syncthreads();   // rst = (r*h)_t (bf16) for the whole cluster

    // phase D: zg-waves -> g, h update, broadcast h_{t+1}
    if (zgw) {
      f32x4 g0 = {0.f, 0.f, 0.f, 0.f}, g1 = {0.f, 0.f, 0.f, 0.f};
      if (t > 0) {
        const unsigned short* wb = &wlds[2][ct * 16 + l15][quad * 8];
        #pragma unroll
        for (int kb = 0; kb < 16; kb += 2) {
          g0 = __builtin_amdgcn_mfma_f32_16x16x32_bf16(
              *(const short8*)&rst[l15][kb * 32 + quad * 8],
              *(const short8*)(wb + kb * 32), g0, 0, 0, 0);
          g1 = __builtin_amdgcn_mfma_f32_16x16x32_bf16(
              *(const short8*)&rst[l15][(kb + 1) * 32 + quad * 8],
              *(const short8*)(wb + (kb + 1) * 32), g1, 0, 0, 0);
        }
      }
      unsigned int* hb = PhT + (size_t)((t + 1) & 1) * 32768 + c * 8192;
      const unsigned int ntag = (unsigned int)(t + 1);
      #pragma unroll
      for (int i = 0; i < 4; ++i) {
        float pre = g0[i] + g1[i] + xg[i];
        float e  = __expf(-2.f * fabsf(pre));   // overflow-safe tanh
        float th = (1.f - e) / (1.f + e);
        th = (pre < 0.f) ? -th : th;
        float hn = zv[i] * hz[i] + (1.f - zv[i]) * th;
        hz[i] = hn;
        size_t ridx = (size_t)(row0 + m_base + i) * 512 + colg;
        dout[(size_t)t * BATCH * 512 + ridx] = hn;
        __hip_atomic_store(&hb[(m_base + i) * 512 + colg],
            ((unsigned int)f2bf(hn) << 16) | ntag,
            __ATOMIC_RELAXED, __HIP_MEMORY_SCOPE_AGENT);
        if (t == T_STEPS - 1)
          dout[(size_t)T_STEPS * BATCH * 512 + ridx] = hn;   // h_final
        if (t == t0 + cs - 1)
          hstateF[ridx] = hn;                                 // chunk carry
      }
    }
  }
}

// ---------------------------------------------------------------- launch
extern "C" void kernel_launch(void* const* d_in, const int* in_sizes, int n_in,
                              void* d_out, int out_size, void* d_ws, size_t ws_size,
                              hipStream_t stream) {
  const float* x  = (const float*)d_in[0];
  const float* Wr = (const float*)d_in[1];
  const float* br = (const float*)d_in[2];
  const float* Wz = (const float*)d_in[3];
  const float* bz = (const float*)d_in[4];
  const float* Wg = (const float*)d_in[5];
  const float* bg = (const float*)d_in[6];
  float* out = (float*)d_out;
  char* ws = (char*)d_ws;

  // ws layout (aligned offsets)
  float* hstateF         = (float*)(ws + 0);                // 128 KB
  unsigned int* PhT      = (unsigned int*)(ws + 131072);    // 256 KB tagged h
  unsigned int* PrhT     = (unsigned int*)(ws + 393216);    // 128 KB tagged rh
  float* bias            = (float*)(ws + 524288);           // 6 KB
  unsigned short* whb    = (unsigned short*)(ws + 532480);  // 1.5 MB
  unsigned short* wxb    = (unsigned short*)(ws + 2105344); // 1.5 MB
  float* xbuf            = (float*)(ws + 3678208);          // cs*64*1536*4

  int cs = T_STEPS;   // largest chunk of timesteps whose Xbuf fits in ws
  while (cs > 8 &&
         3678208ull + (unsigned long long)cs * 64 * 1536 * 4 >
             (unsigned long long)ws_size)
    cs >>= 1;

  // tag-clean the exchange buffers (tag 0 never matches any expected t>=1)
  hipMemsetAsync((void*)(ws + 131072), 0, 393216, stream);
  prep_weights<<<1536, 256, 0, stream>>>(Wr, br, Wz, bz, Wg, bg, whb, wxb, bias);
  for (int t0 = 0; t0 < T_STEPS; t0 += cs) {
    xpre_gemm<<<dim3((cs * 64) / 128, 12), 256, 0, stream>>>(
        x + (size_t)t0 * 64 * 512, wxb, bias, xbuf);
    gru_rec<<<64, 256, 0, stream>>>(xbuf, whb, out, hstateF, PhT, PrhT,
                                    t0, cs);
  }
}